// Round 18
// baseline (63.508 us; speedup 1.0000x reference)
//
#include <hip/hip_runtime.h>

typedef __bf16 bf16x8 __attribute__((ext_vector_type(8)));
typedef float f32x4 __attribute__((ext_vector_type(4)));
typedef unsigned short u16x8 __attribute__((ext_vector_type(8)));
typedef unsigned short u16x4 __attribute__((ext_vector_type(4)));

#define B_ 32
#define CC 512
#define HW 192
#define C8_ 64
#define NTRI 528
#define NBLK 656          // 528 gram + 128 qk-proj, = 8*82
#define FB 24576          // one buffer: A(192x32) + B(192x32) bf16, 64B rows

__device__ inline unsigned short f2bf(float f) {
    unsigned u = __float_as_uint(f);
    unsigned r = (u + 0x7FFFu + ((u >> 16) & 1u)) >> 16;
    return (unsigned short)r;
}

__device__ inline void gload16(const void* g, void* l) {
    __builtin_amdgcn_global_load_lds(
        (const __attribute__((address_space(1))) unsigned*)g,
        (__attribute__((address_space(3))) unsigned*)l,
        16, 0, 0);
}

// ---------------- Kernel 1 (fused prep): transpose + weight precast ---------
__global__ void prep(const float* __restrict__ x,
                     const float* __restrict__ Wq, const float* __restrict__ Wk,
                     unsigned short* __restrict__ xt,
                     unsigned short* __restrict__ wqb, unsigned short* __restrict__ wkb) {
    __shared__ unsigned short tile[64 * 64];
    int t = threadIdx.x;
    if (blockIdx.x >= 96) {
        int id = (blockIdx.x - 96) * 8 + blockIdx.y;     // 0..63
        const float* src = (id < 32) ? Wq : Wk;
        unsigned short* dst = (id < 32) ? wqb : wkb;
        int base = (id & 31) * 1024 + t * 4;
        f32x4 a = *(const f32x4*)(src + base);
        u16x4 o;
        #pragma unroll
        for (int e = 0; e < 4; ++e) o[e] = f2bf(a[e]);
        *(u16x4*)(dst + base) = o;
        return;
    }
    int b = blockIdx.x / 3, mt = blockIdx.x % 3;
    int m0 = mt * 64, c0 = blockIdx.y * 64;
    const float* xb = x + (size_t)b * CC * HW + (size_t)c0 * HW + m0;

    int mq = t & 15, cl0 = t >> 4;
    int sw = (mq & 7) << 3;
    #pragma unroll
    for (int rd = 0; rd < 4; ++rd) {
        int cl = rd * 16 + cl0;
        f32x4 v = *(const f32x4*)(xb + cl * HW + mq * 4);
        #pragma unroll
        for (int e = 0; e < 4; ++e)
            tile[(mq * 4 + e) * 64 + (cl ^ sw)] = f2bf(v[e]);
    }
    __syncthreads();
    unsigned short* xo = xt + ((size_t)b * HW + m0) * CC + c0;
    int kc = t & 7, mr0 = t >> 3;
    #pragma unroll
    for (int rd = 0; rd < 2; ++rd) {
        int mr = rd * 32 + mr0;
        u16x8 v = *(const u16x8*)&tile[mr * 64 + ((kc << 3) ^ (((mr >> 2) & 7) << 3))];
        *(u16x8*)(xo + (size_t)mr * CC + kc * 8) = v;
    }
}

// ---------------- Kernel 2 (fused): gram full-tiles + q/k projections -------
// raw blocks 0..527: full 192x192 pair-tile, 8 waves (4x2) of 48x96, BK=32
//   dbuf drain-barrier, 2 blocks/CU. Both maxes complete in-block.
// raw blocks 528..655: q/k projection (b, mgrp) — dispatched last, backfills.
__global__ __launch_bounds__(512, 4) void gram_qk(
        const unsigned short* __restrict__ xt,
        const unsigned short* __restrict__ wqb, const unsigned short* __restrict__ wkb,
        const float* __restrict__ bq, const float* __restrict__ bk,
        unsigned short* __restrict__ qo, unsigned short* __restrict__ ko,
        float* __restrict__ out) {
    __shared__ __attribute__((aligned(16))) char smem[2 * FB];

    int tid = threadIdx.x;
    int w = tid >> 6, lane = tid & 63;
    int l15 = lane & 15, lq = lane >> 4;

    if (blockIdx.x < NTRI) {
        // ================= GRAM (full pair-tile) =================
        int bid = (blockIdx.x & 7) * 66 + (blockIdx.x >> 3);   // 528 = 8*66
        int idx = bid, g = 0;
        while (idx >= B_ - g) { idx -= B_ - g; ++g; }
        int p = g + idx;

        const unsigned short* xg = xt + (size_t)g * HW * CC;
        const unsigned short* xp = xt + (size_t)p * HW * CC;

        int wr = w >> 1, wc = w & 1;                // 4 x 2 wave grid, 48x96 each

        // staging: 1536 chunks of 16B per buffer (A rows 0..191, B rows 0..191),
        // 3 per thread: q = tid + 512*ci. q<768: A (row q>>2, slot q&3); else B.
        // Source pre-applies inverse swizzle: logical chunk s ^ ((row>>1)&3).
        const unsigned short* sp[3];
        unsigned lo[3];
        #pragma unroll
        for (int ci = 0; ci < 3; ++ci) {
            int q = tid + 512 * ci;
            lo[ci] = (unsigned)q * 16;
            int q2 = (q < 768) ? q : q - 768;
            int r = q2 >> 2, s = q2 & 3;
            sp[ci] = ((q < 768) ? xg : xp) + r * CC + ((s ^ ((r >> 1) & 3)) << 3);
        }

        // read offsets (byte): region + row*64 + ((lq ^ ((row>>1)&3))<<4)
        unsigned aoff[3], boff[6];
        #pragma unroll
        for (int i = 0; i < 3; ++i) {
            int row = wr * 48 + i * 16 + l15;                    // 0..191
            aoff[i] = (unsigned)row * 64 + ((unsigned)(lq ^ ((row >> 1) & 3)) << 4);
        }
        #pragma unroll
        for (int j = 0; j < 6; ++j) {
            int n = wc * 96 + j * 16 + l15;                      // 0..191
            boff[j] = 12288u + (unsigned)n * 64 + ((unsigned)(lq ^ ((n >> 1) & 3)) << 4);
        }

        f32x4 acc[3][6];
        #pragma unroll
        for (int i = 0; i < 3; ++i)
            #pragma unroll
            for (int j = 0; j < 6; ++j)
                acc[i][j] = (f32x4){0.f, 0.f, 0.f, 0.f};

        #define STG(buf, kt)                                                   \
            {                                                                  \
                char* base = smem + (buf) * FB;                                \
                int k0 = (kt) * 32;                                            \
                gload16(sp[0] + k0, base + lo[0]);                             \
                gload16(sp[1] + k0, base + lo[1]);                             \
                gload16(sp[2] + k0, base + lo[2]);                             \
            }

        #define CMP(buf)                                                       \
            {                                                                  \
                const char* Bb = smem + (buf) * FB;                            \
                bf16x8 af[3], bfr[6];                                          \
                _Pragma("unroll")                                              \
                for (int i = 0; i < 3; ++i)                                    \
                    af[i] = *(const bf16x8*)(Bb + aoff[i]);                    \
                _Pragma("unroll")                                              \
                for (int j = 0; j < 6; ++j)                                    \
                    bfr[j] = *(const bf16x8*)(Bb + boff[j]);                   \
                _Pragma("unroll")                                              \
                for (int i = 0; i < 3; ++i)                                    \
                    _Pragma("unroll")                                          \
                    for (int j = 0; j < 6; ++j)                                \
                        acc[i][j] = __builtin_amdgcn_mfma_f32_16x16x32_bf16(   \
                            af[i], bfr[j], acc[i][j], 0, 0, 0);                \
            }

        STG(0, 0);
        __syncthreads();
        for (int kt = 0; kt < 16; ++kt) {
            int cur = kt & 1;
            if (kt < 15) STG(cur ^ 1, kt + 1);
            CMP(cur);
            __syncthreads();
        }

        // ---- epilogue (aliases smem; all K-loop LDS traffic done)
        float* rowbuf = (float*)smem;            // [2][192] partial over wc
        float* colbuf = (float*)(smem + 1536);   // [4][192] partial over wr

        #pragma unroll
        for (int i = 0; i < 3; ++i) {            // rowmax over this wave's 96 n
            float rm[4];
            #pragma unroll
            for (int r = 0; r < 4; ++r) rm[r] = -1e30f;
            #pragma unroll
            for (int j = 0; j < 6; ++j)
                #pragma unroll
                for (int r = 0; r < 4; ++r)
                    rm[r] = fmaxf(rm[r], acc[i][j][r]);
            #pragma unroll
            for (int msk = 1; msk <= 8; msk <<= 1)
                #pragma unroll
                for (int r = 0; r < 4; ++r)
                    rm[r] = fmaxf(rm[r], __shfl_xor(rm[r], msk));
            if (l15 == 0) {
                #pragma unroll
                for (int r = 0; r < 4; ++r)
                    rowbuf[wc * HW + wr * 48 + i * 16 + lq * 4 + r] = rm[r];
            }
        }
        #pragma unroll
        for (int j = 0; j < 6; ++j) {            // colmax over this wave's 48 m
            float cm = -1e30f;
            #pragma unroll
            for (int i = 0; i < 3; ++i)
                #pragma unroll
                for (int r = 0; r < 4; ++r)
                    cm = fmaxf(cm, acc[i][j][r]);
            cm = fmaxf(cm, __shfl_xor(cm, 16));
            cm = fmaxf(cm, __shfl_xor(cm, 32));
            if (lane < 16) colbuf[wr * HW + wc * 96 + j * 16 + l15] = cm;
        }
        __syncthreads();
        if (tid < HW) {
            float rmax = fmaxf(rowbuf[tid], rowbuf[HW + tid]);
            out[((size_t)p * B_ + g) * HW + tid] = rmax;
            float cmax = fmaxf(fmaxf(colbuf[tid], colbuf[HW + tid]),
                               fmaxf(colbuf[2 * HW + tid], colbuf[3 * HW + tid]));
            out[((size_t)g * B_ + p) * HW + tid] = cmax;   // same addr if g==p
        }
    } else {
        // ================= q/k projection (b, mgrp) =================
        int pb = blockIdx.x - NTRI;             // 0..127
        int b = pb >> 2, m0 = (pb & 3) * 48;
        int w4 = w & 3;
        int qc = w4 * 16 + l15;
        bool isq = (w < 4);
        const unsigned short* wp = (isq ? wqb : wkb) + (size_t)qc * CC;
        float bias = isq ? bq[qc] : bk[qc];
        unsigned short* dst = isq ? qo : ko;
        const unsigned short* xb = xt + ((size_t)b * HW + m0) * CC;

        f32x4 a3[3];
        #pragma unroll
        for (int i = 0; i < 3; ++i) a3[i] = (f32x4){0.f, 0.f, 0.f, 0.f};
        for (int kt = 0; kt < 16; ++kt) {
            int ko8 = kt * 32 + lq * 8;
            bf16x8 wf = *(const bf16x8*)(wp + ko8);
            #pragma unroll
            for (int i = 0; i < 3; ++i) {
                bf16x8 af = *(const bf16x8*)(xb + (i * 16 + l15) * CC + ko8);
                a3[i] = __builtin_amdgcn_mfma_f32_16x16x32_bf16(af, wf, a3[i], 0, 0, 0);
            }
        }
        #pragma unroll
        for (int i = 0; i < 3; ++i) {
            #pragma unroll
            for (int r = 0; r < 4; ++r) {
                int m = m0 + i * 16 + lq * 4 + r;
                dst[((size_t)b * HW + m) * C8_ + qc] = f2bf(a3[i][r] + bias);
            }
        }
    }
}

// ---------------- Kernel 3: energy = q k^T per batch, fused row-max ---------
__global__ __launch_bounds__(256) void pam_energy(
        const unsigned short* __restrict__ qo,
        const unsigned short* __restrict__ ko,
        float* __restrict__ out) {
    int b = blockIdx.x, m0 = blockIdx.y * 48;
    int tid = threadIdx.x, w = tid >> 6, lane = tid & 63;
    int l15 = lane & 15, lq = lane >> 4;
    int n0 = w * 48;

    f32x4 acc[3][3];
    #pragma unroll
    for (int i = 0; i < 3; ++i)
        #pragma unroll
        for (int j = 0; j < 3; ++j)
            acc[i][j] = (f32x4){0.f, 0.f, 0.f, 0.f};

    const unsigned short* qb = qo + ((size_t)b * HW + m0) * C8_;
    const unsigned short* kb = ko + ((size_t)b * HW + n0) * C8_;

    #pragma unroll
    for (int kt = 0; kt < 2; ++kt) {
        int ko8 = kt * 32 + lq * 8;
        bf16x8 af[3], bfr[3];
        #pragma unroll
        for (int i = 0; i < 3; ++i)
            af[i] = *(const bf16x8*)(qb + (i * 16 + l15) * C8_ + ko8);
        #pragma unroll
        for (int j = 0; j < 3; ++j)
            bfr[j] = *(const bf16x8*)(kb + (j * 16 + l15) * C8_ + ko8);
        #pragma unroll
        for (int i = 0; i < 3; ++i)
            #pragma unroll
            for (int j = 0; j < 3; ++j)
                acc[i][j] = __builtin_amdgcn_mfma_f32_16x16x32_bf16(af[i], bfr[j], acc[i][j], 0, 0, 0);
    }

    __shared__ float red[4][48];
    #pragma unroll
    for (int i = 0; i < 3; ++i) {
        float rm[4];
        #pragma unroll
        for (int r = 0; r < 4; ++r) rm[r] = -1e30f;
        #pragma unroll
        for (int j = 0; j < 3; ++j)
            #pragma unroll
            for (int r = 0; r < 4; ++r)
                rm[r] = fmaxf(rm[r], acc[i][j][r]);
        #pragma unroll
        for (int msk = 1; msk <= 8; msk <<= 1)
            #pragma unroll
            for (int r = 0; r < 4; ++r)
                rm[r] = fmaxf(rm[r], __shfl_xor(rm[r], msk));
        if (l15 == 0) {
            #pragma unroll
            for (int r = 0; r < 4; ++r)
                red[w][i * 16 + lq * 4 + r] = rm[r];
        }
    }
    __syncthreads();
    if (tid < 48) {
        float v = fmaxf(fmaxf(red[0][tid], red[1][tid]),
                        fmaxf(red[2][tid], red[3][tid]));
        out[((size_t)B_ * B_ + b) * HW + m0 + tid] = v;
    }
}

extern "C" void kernel_launch(void* const* d_in, const int* in_sizes, int n_in,
                              void* d_out, int out_size, void* d_ws, size_t ws_size,
                              hipStream_t stream) {
    (void)in_sizes; (void)n_in; (void)out_size; (void)ws_size;
    const float* x  = (const float*)d_in[0];
    const float* Wq = (const float*)d_in[1];
    const float* bq = (const float*)d_in[2];
    const float* Wk = (const float*)d_in[3];
    const float* bk = (const float*)d_in[4];
    float* out = (float*)d_out;

    char* ws = (char*)d_ws;
    unsigned short* xt  = (unsigned short*)ws;                        // 6291456 B
    unsigned short* wqb = (unsigned short*)(ws + 6291456);            // 65536 B
    unsigned short* wkb = (unsigned short*)(ws + 6291456 + 65536);    // 65536 B
    unsigned short* qbuf = (unsigned short*)(ws + 6291456 + 131072);  // 786432 B
    unsigned short* kbuf = (unsigned short*)(ws + 6291456 + 131072 + 786432);

    prep<<<dim3(104, 8), dim3(256), 0, stream>>>(x, Wq, Wk, xt, wqb, wkb);
    gram_qk<<<dim3(NBLK), dim3(512), 0, stream>>>(
        xt, wqb, wkb, bq, bk, qbuf, kbuf, out);
    pam_energy<<<dim3(32, 4), dim3(256), 0, stream>>>(qbuf, kbuf, out);
}

// Round 19
// 51.807 us; speedup vs baseline: 1.2259x; 1.2259x over previous
//
#include <hip/hip_runtime.h>

typedef __bf16 bf16x8 __attribute__((ext_vector_type(8)));
typedef float f32x4 __attribute__((ext_vector_type(4)));
typedef unsigned short u16x8 __attribute__((ext_vector_type(8)));
typedef unsigned short u16x4 __attribute__((ext_vector_type(4)));

#define B_ 32
#define CC 512
#define HW 192
#define C8_ 64
#define NTRI 528
#define NG2 1056          // 2 half-tiles per pair (gram); raw blocks >=1056: qk-proj
#define BUF_B 36864       // one buffer: A(96x64) + B(192x64) bf16, 128B rows
#define SMEM_BYTES 73728  // 2 buffers

__device__ inline unsigned short f2bf(float f) {
    unsigned u = __float_as_uint(f);
    unsigned r = (u + 0x7FFFu + ((u >> 16) & 1u)) >> 16;
    return (unsigned short)r;
}

__device__ inline void gload16(const void* g, void* l) {
    __builtin_amdgcn_global_load_lds(
        (const __attribute__((address_space(1))) unsigned*)g,
        (__attribute__((address_space(3))) unsigned*)l,
        16, 0, 0);
}

// ---------------- Kernel 1 (fused prep): transpose + weight precast ---------
__global__ void prep(const float* __restrict__ x,
                     const float* __restrict__ Wq, const float* __restrict__ Wk,
                     unsigned short* __restrict__ xt,
                     unsigned short* __restrict__ wqb, unsigned short* __restrict__ wkb) {
    __shared__ unsigned short tile[64 * 64];
    int t = threadIdx.x;
    if (blockIdx.x >= 96) {
        int id = (blockIdx.x - 96) * 8 + blockIdx.y;     // 0..63
        const float* src = (id < 32) ? Wq : Wk;
        unsigned short* dst = (id < 32) ? wqb : wkb;
        int base = (id & 31) * 1024 + t * 4;
        f32x4 a = *(const f32x4*)(src + base);
        u16x4 o;
        #pragma unroll
        for (int e = 0; e < 4; ++e) o[e] = f2bf(a[e]);
        *(u16x4*)(dst + base) = o;
        return;
    }
    int b = blockIdx.x / 3, mt = blockIdx.x % 3;
    int m0 = mt * 64, c0 = blockIdx.y * 64;
    const float* xb = x + (size_t)b * CC * HW + (size_t)c0 * HW + m0;

    int mq = t & 15, cl0 = t >> 4;
    int sw = (mq & 7) << 3;
    #pragma unroll
    for (int rd = 0; rd < 4; ++rd) {
        int cl = rd * 16 + cl0;
        f32x4 v = *(const f32x4*)(xb + cl * HW + mq * 4);
        #pragma unroll
        for (int e = 0; e < 4; ++e)
            tile[(mq * 4 + e) * 64 + (cl ^ sw)] = f2bf(v[e]);
    }
    __syncthreads();
    unsigned short* xo = xt + ((size_t)b * HW + m0) * CC + c0;
    int kc = t & 7, mr0 = t >> 3;
    #pragma unroll
    for (int rd = 0; rd < 2; ++rd) {
        int mr = rd * 32 + mr0;
        u16x8 v = *(const u16x8*)&tile[mr * 64 + ((kc << 3) ^ (((mr >> 2) & 7) << 3))];
        *(u16x8*)(xo + (size_t)mr * CC + kc * 8) = v;
    }
}

// ---------------- Kernel 2 (fused): gram half-tiles + q/k projections -------
// raw blocks 0..1055: gram half-tile (96x192), R11-verbatim (best measured).
// raw blocks 1056..1183: q/k projection for (b, mgrp) — dispatched last,
// backfills gram's tail; round-robin XCD placement (no swizzle clustering).
__global__ __launch_bounds__(512, 4) void gram_qk(
        const unsigned short* __restrict__ xt,
        const unsigned short* __restrict__ wqb, const unsigned short* __restrict__ wkb,
        const float* __restrict__ bq, const float* __restrict__ bk,
        unsigned short* __restrict__ qo, unsigned short* __restrict__ ko,
        float* __restrict__ out, float* __restrict__ ws2) {
    extern __shared__ char smem[];

    int tid = threadIdx.x;
    int w = tid >> 6, lane = tid & 63;
    int l15 = lane & 15, lq = lane >> 4;

    if (blockIdx.x < NG2) {
        // ================= GRAM (R11 verbatim) =================
        int bid = (blockIdx.x & 7) * 132 + (blockIdx.x >> 3);   // 1056 = 8*132
        int pairid = bid >> 1, h = bid & 1;
        int idx = pairid, g = 0;
        while (idx >= B_ - g) { idx -= B_ - g; ++g; }
        int p = g + idx;

        const unsigned short* xga = xt + ((size_t)g * HW + 96 * h) * CC;  // A: 96 rows
        const unsigned short* xp  = xt + (size_t)p * HW * CC;             // B: 192 rows

        int wr = w >> 2, wc = w & 3;                // 2 x 4 wave grid

        const unsigned short* sp[5];
        unsigned lo[5];
        #pragma unroll
        for (int ci = 0; ci < 5; ++ci) {
            int R = (ci < 4) ? (w + 8 * ci) : (32 + w);
            int q = R * 64 + lane;
            if (ci == 4 && w >= 4) q = lane;        // dummy (unused)
            lo[ci] = (unsigned)q * 16;
            if (q < 768) {
                int r = q >> 3, s = q & 7;
                sp[ci] = xga + r * CC + ((s ^ (r & 7)) << 3);
            } else {
                int q2 = q - 768, n = q2 >> 3, s = q2 & 7;
                sp[ci] = xp + n * CC + ((s ^ (n & 7)) << 3);
            }
        }

        unsigned aoff[3], boff[3];
        #pragma unroll
        for (int i = 0; i < 3; ++i) {
            int row = wr * 48 + i * 16 + l15;                    // 0..95
            aoff[i] = (unsigned)row * 128 + ((unsigned)(lq ^ (row & 7)) << 4);
        }
        #pragma unroll
        for (int j = 0; j < 3; ++j) {
            int n = wc * 48 + j * 16 + l15;                      // 0..191
            boff[j] = 12288u + (unsigned)n * 128 + ((unsigned)(lq ^ (n & 7)) << 4);
        }

        f32x4 acc[3][3];
        #pragma unroll
        for (int i = 0; i < 3; ++i)
            #pragma unroll
            for (int j = 0; j < 3; ++j)
                acc[i][j] = (f32x4){0.f, 0.f, 0.f, 0.f};

        #define STG2(buf, kt)                                                  \
            {                                                                  \
                char* base = smem + (buf) * BUF_B;                             \
                int k0 = (kt) * 64;                                            \
                gload16(sp[0] + k0, base + lo[0]);                             \
                gload16(sp[1] + k0, base + lo[1]);                             \
                gload16(sp[2] + k0, base + lo[2]);                             \
                gload16(sp[3] + k0, base + lo[3]);                             \
                if (w < 4) gload16(sp[4] + k0, base + lo[4]);                  \
            }

        #define CMP2(buf)                                                      \
            {                                                                  \
                const char* Bb = smem + (buf) * BUF_B;                         \
                _Pragma("unroll")                                              \
                for (int kx = 0; kx < 128; kx += 64) {                         \
                    bf16x8 af[3], bfr[3];                                      \
                    _Pragma("unroll")                                          \
                    for (int i = 0; i < 3; ++i)                                \
                        af[i] = *(const bf16x8*)(Bb + (aoff[i] ^ kx));         \
                    _Pragma("unroll")                                          \
                    for (int j = 0; j < 3; ++j)                                \
                        bfr[j] = *(const bf16x8*)(Bb + (boff[j] ^ kx));        \
                    _Pragma("unroll")                                          \
                    for (int i = 0; i < 3; ++i)                                \
                        _Pragma("unroll")                                      \
                        for (int j = 0; j < 3; ++j)                            \
                            acc[i][j] = __builtin_amdgcn_mfma_f32_16x16x32_bf16( \
                                af[i], bfr[j], acc[i][j], 0, 0, 0);            \
                }                                                              \
            }

        STG2(0, 0);
        __syncthreads();
        for (int kt = 0; kt < 8; ++kt) {
            int cur = kt & 1;
            if (kt < 7) STG2(cur ^ 1, kt + 1);
            CMP2(cur);
            __syncthreads();
        }

        // ---- epilogue (buffers reusable after final sync)
        float* rowbuf = (float*)smem;            // [4][96]
        float* colbuf = (float*)(smem + 1536);   // [2][192]

        #pragma unroll
        for (int i = 0; i < 3; ++i) {            // rowmax over n (full 192)
            float rm[4];
            #pragma unroll
            for (int r = 0; r < 4; ++r) rm[r] = -1e30f;
            #pragma unroll
            for (int j = 0; j < 3; ++j)
                #pragma unroll
                for (int r = 0; r < 4; ++r)
                    rm[r] = fmaxf(rm[r], acc[i][j][r]);
            #pragma unroll
            for (int msk = 1; msk <= 8; msk <<= 1)
                #pragma unroll
                for (int r = 0; r < 4; ++r)
                    rm[r] = fmaxf(rm[r], __shfl_xor(rm[r], msk));
            if (l15 == 0) {
                #pragma unroll
                for (int r = 0; r < 4; ++r)
                    rowbuf[wc * 96 + wr * 48 + i * 16 + lq * 4 + r] = rm[r];
            }
        }
        #pragma unroll
        for (int j = 0; j < 3; ++j) {            // colmax over m (96 rows, partial)
            float cm = -1e30f;
            #pragma unroll
            for (int i = 0; i < 3; ++i)
                #pragma unroll
                for (int r = 0; r < 4; ++r)
                    cm = fmaxf(cm, acc[i][j][r]);
            cm = fmaxf(cm, __shfl_xor(cm, 16));
            cm = fmaxf(cm, __shfl_xor(cm, 32));
            if (lane < 16) colbuf[wr * HW + wc * 48 + j * 16 + l15] = cm;
        }
        __syncthreads();
        if (tid < 96) {
            float v = fmaxf(fmaxf(rowbuf[tid], rowbuf[96 + tid]),
                            fmaxf(rowbuf[192 + tid], rowbuf[288 + tid]));
            out[((size_t)p * B_ + g) * HW + 96 * h + tid] = v;
        }
        if (tid >= 128 && tid < 320) {
            int n = tid - 128;
            ws2[(size_t)pairid * 384 + h * 192 + n] = fmaxf(colbuf[n], colbuf[HW + n]);
        }
    } else {
        // ================= q/k projection (b, mgrp) =================
        int pb = blockIdx.x - NG2;              // 0..127
        int b = pb >> 2, m0 = (pb & 3) * 48;
        int w4 = w & 3;
        int qc = w4 * 16 + l15;
        bool isq = (w < 4);
        const unsigned short* wp = (isq ? wqb : wkb) + (size_t)qc * CC;
        float bias = isq ? bq[qc] : bk[qc];
        unsigned short* dst = isq ? qo : ko;
        const unsigned short* xb = xt + ((size_t)b * HW + m0) * CC;

        f32x4 a3[3];
        #pragma unroll
        for (int i = 0; i < 3; ++i) a3[i] = (f32x4){0.f, 0.f, 0.f, 0.f};
        for (int kt = 0; kt < 16; ++kt) {
            int ko8 = kt * 32 + lq * 8;
            bf16x8 wf = *(const bf16x8*)(wp + ko8);
            #pragma unroll
            for (int i = 0; i < 3; ++i) {
                bf16x8 af = *(const bf16x8*)(xb + (i * 16 + l15) * CC + ko8);
                a3[i] = __builtin_amdgcn_mfma_f32_16x16x32_bf16(af, wf, a3[i], 0, 0, 0);
            }
        }
        #pragma unroll
        for (int i = 0; i < 3; ++i) {
            #pragma unroll
            for (int r = 0; r < 4; ++r) {
                int m = m0 + i * 16 + lq * 4 + r;
                dst[((size_t)b * HW + m) * C8_ + qc] = f2bf(a3[i][r] + bias);
            }
        }
    }
}

// ---------------- Kernel 3 (fused): pam_energy (0..127) + finalize (128..655)
__global__ __launch_bounds__(256) void energy_fin(
        const unsigned short* __restrict__ qo,
        const unsigned short* __restrict__ ko,
        const float* __restrict__ ws2,
        float* __restrict__ out) {
    int tid = threadIdx.x;
    if (blockIdx.x >= 128) {
        int pairid = blockIdx.x - 128;
        int idx = pairid, g = 0;
        while (idx >= B_ - g) { idx -= B_ - g; ++g; }
        int p = g + idx;
        if (tid < HW)
            out[((size_t)g * B_ + p) * HW + tid] =
                fmaxf(ws2[(size_t)pairid * 384 + tid], ws2[(size_t)pairid * 384 + 192 + tid]);
        return;
    }
    int b = blockIdx.x >> 2, m0 = (blockIdx.x & 3) * 48;
    int w = tid >> 6, lane = tid & 63;
    int l15 = lane & 15, lq = lane >> 4;
    int n0 = w * 48;

    f32x4 acc[3][3];
    #pragma unroll
    for (int i = 0; i < 3; ++i)
        #pragma unroll
        for (int j = 0; j < 3; ++j)
            acc[i][j] = (f32x4){0.f, 0.f, 0.f, 0.f};

    const unsigned short* qb = qo + ((size_t)b * HW + m0) * C8_;
    const unsigned short* kb = ko + ((size_t)b * HW + n0) * C8_;

    #pragma unroll
    for (int kt = 0; kt < 2; ++kt) {
        int ko8 = kt * 32 + lq * 8;
        bf16x8 af[3], bfr[3];
        #pragma unroll
        for (int i = 0; i < 3; ++i)
            af[i] = *(const bf16x8*)(qb + (i * 16 + l15) * C8_ + ko8);
        #pragma unroll
        for (int j = 0; j < 3; ++j)
            bfr[j] = *(const bf16x8*)(kb + (j * 16 + l15) * C8_ + ko8);
        #pragma unroll
        for (int i = 0; i < 3; ++i)
            #pragma unroll
            for (int j = 0; j < 3; ++j)
                acc[i][j] = __builtin_amdgcn_mfma_f32_16x16x32_bf16(af[i], bfr[j], acc[i][j], 0, 0, 0);
    }

    __shared__ float red[4][48];
    #pragma unroll
    for (int i = 0; i < 3; ++i) {
        float rm[4];
        #pragma unroll
        for (int r = 0; r < 4; ++r) rm[r] = -1e30f;
        #pragma unroll
        for (int j = 0; j < 3; ++j)
            #pragma unroll
            for (int r = 0; r < 4; ++r)
                rm[r] = fmaxf(rm[r], acc[i][j][r]);
        #pragma unroll
        for (int msk = 1; msk <= 8; msk <<= 1)
            #pragma unroll
            for (int r = 0; r < 4; ++r)
                rm[r] = fmaxf(rm[r], __shfl_xor(rm[r], msk));
        if (l15 == 0) {
            #pragma unroll
            for (int r = 0; r < 4; ++r)
                red[w][i * 16 + lq * 4 + r] = rm[r];
        }
    }
    __syncthreads();
    if (tid < 48) {
        float v = fmaxf(fmaxf(red[0][tid], red[1][tid]),
                        fmaxf(red[2][tid], red[3][tid]));
        out[((size_t)B_ * B_ + b) * HW + m0 + tid] = v;
    }
}

extern "C" void kernel_launch(void* const* d_in, const int* in_sizes, int n_in,
                              void* d_out, int out_size, void* d_ws, size_t ws_size,
                              hipStream_t stream) {
    (void)in_sizes; (void)n_in; (void)out_size; (void)ws_size;
    const float* x  = (const float*)d_in[0];
    const float* Wq = (const float*)d_in[1];
    const float* bq = (const float*)d_in[2];
    const float* Wk = (const float*)d_in[3];
    const float* bk = (const float*)d_in[4];
    float* out = (float*)d_out;

    char* ws = (char*)d_ws;
    unsigned short* xt  = (unsigned short*)ws;                        // 6291456 B
    unsigned short* wqb = (unsigned short*)(ws + 6291456);            // 65536 B
    unsigned short* wkb = (unsigned short*)(ws + 6291456 + 65536);    // 65536 B
    unsigned short* qbuf = (unsigned short*)(ws + 6291456 + 131072);  // 786432 B
    unsigned short* kbuf = (unsigned short*)(ws + 6291456 + 131072 + 786432);
    float* ws2 = (float*)(ws + 6291456 + 131072 + 2 * 786432);        // 811008 B

    hipFuncSetAttribute((const void*)gram_qk,
                        hipFuncAttributeMaxDynamicSharedMemorySize, SMEM_BYTES);

    prep<<<dim3(104, 8), dim3(256), 0, stream>>>(x, Wq, Wk, xt, wqb, wkb);
    gram_qk<<<dim3(NG2 + 128), dim3(512), SMEM_BYTES, stream>>>(
        xt, wqb, wkb, bq, bk, qbuf, kbuf, out, ws2);
    energy_fin<<<dim3(656), dim3(256), 0, stream>>>(qbuf, kbuf, ws2, out);
}